// Round 18
// baseline (462.220 us; speedup 1.0000x reference)
//
#include <hip/hip_runtime.h>
#include <hip/hip_bf16.h>
#include <math.h>

#define SS 2048
#define HH 1024
#define NHEADS 16
#define NKVH 4
#define HDIM 64
#define NEXP 8
#define FDIM 2048

static constexpr float EPSV   = 1e-6f;
static constexpr float ALPHAV = 1.702f;
static constexpr float LIMITV = 7.0f;

typedef __attribute__((ext_vector_type(8))) short bf16x8;
typedef __attribute__((ext_vector_type(4))) float f32x4;

__device__ __forceinline__ float wave_reduce_sum(float v) {
#pragma unroll
  for (int off = 32; off; off >>= 1) v += __shfl_xor(v, off);
  return v;
}

__device__ __forceinline__ unsigned short bf16_bits(float x) {
  __hip_bfloat16 h = __float2bfloat16(x);
  return *reinterpret_cast<unsigned short*>(&h);
}

__device__ __forceinline__ float bf16u_to_f(unsigned short u) {
  union { unsigned int i; float f; } c;
  c.i = ((unsigned int)u) << 16;
  return c.f;
}

__device__ __forceinline__ void gload_lds16(const __hip_bfloat16* g, __hip_bfloat16* s) {
  __builtin_amdgcn_global_load_lds(
      (const __attribute__((address_space(1))) void*)g,
      (__attribute__((address_space(3))) void*)s, 16, 0, 0);
}

// ---------------- RMSNorm: fp32 in, optional fp32 out + bf16 out -----------
__global__ void rmsnorm_kernel(const float* __restrict__ x,
                               const float* __restrict__ w,
                               float* __restrict__ o32,
                               __hip_bfloat16* __restrict__ o16) {
  int row = blockIdx.x;
  int t = threadIdx.x;
  const float4 v = ((const float4*)(x + (size_t)row * HH))[t];
  float ss = v.x * v.x + v.y * v.y + v.z * v.z + v.w * v.w;
  ss = wave_reduce_sum(ss);
  __shared__ float parts[4];
  if ((t & 63) == 0) parts[t >> 6] = ss;
  __syncthreads();
  float tot = parts[0] + parts[1] + parts[2] + parts[3];
  float r = rsqrtf(tot * (1.0f / HH) + EPSV);
  const float4 ww = ((const float4*)w)[t];
  float4 out;
  out.x = v.x * r * ww.x;
  out.y = v.y * r * ww.y;
  out.z = v.z * r * ww.z;
  out.w = v.w * r * ww.w;
  if (o32) ((float4*)(o32 + (size_t)row * HH))[t] = out;
  __hip_bfloat16* d = o16 + (size_t)row * HH + t * 4;
  d[0] = __float2bfloat16(out.x);
  d[1] = __float2bfloat16(out.y);
  d[2] = __float2bfloat16(out.z);
  d[3] = __float2bfloat16(out.w);
}

// ---------------- Transpose-cast 64x64 core --------------------------------
__device__ __forceinline__ void tcast_body(
    const float* __restrict__ ip, __hip_bfloat16* __restrict__ op,
    int R, int C, int bx, int by, int tid) {
  __shared__ float tile[64][65];
  int c0 = bx * 64, r0 = by * 64;
  int tx = tid & 15, ty = tid >> 4;
#pragma unroll
  for (int j = 0; j < 4; ++j) {
    int row = ty + j * 16;
    float4 v = *(const float4*)(ip + (size_t)(r0 + row) * C + c0 + tx * 4);
    tile[row][tx * 4 + 0] = v.x;
    tile[row][tx * 4 + 1] = v.y;
    tile[row][tx * 4 + 2] = v.z;
    tile[row][tx * 4 + 3] = v.w;
  }
  __syncthreads();
#pragma unroll
  for (int j = 0; j < 4; ++j) {
    int crow = ty + j * 16;
    ushort4 o;
    o.x = bf16_bits(tile[tx * 4 + 0][crow]);
    o.y = bf16_bits(tile[tx * 4 + 1][crow]);
    o.z = bf16_bits(tile[tx * 4 + 2][crow]);
    o.w = bf16_bits(tile[tx * 4 + 3][crow]);
    *(ushort4*)(op + (size_t)(c0 + crow) * R + r0 + tx * 4) = o;
  }
}

// ---------------- Fused 4-weight transpose-cast (attention weights) --------
__global__ __launch_bounds__(256) void tcast4_kernel(
    const float* __restrict__ wq, const float* __restrict__ wk,
    const float* __restrict__ wv, const float* __restrict__ wo,
    __hip_bfloat16* __restrict__ qkvT, __hip_bfloat16* __restrict__ woT) {
  int z = blockIdx.z;
  const float* in;
  __hip_bfloat16* out;
  int C;
  if (z == 0)      { in = wq; out = qkvT;                C = 1024; }
  else if (z == 1) { in = wk; out = qkvT + 1024 * 1024;  C = 256; }
  else if (z == 2) { in = wv; out = qkvT + 1280 * 1024;  C = 256; }
  else             { in = wo; out = woT;                 C = 1024; }
  if (blockIdx.x * 64 >= C) return;
  tcast_body(in, out, 1024, C, blockIdx.x, blockIdx.y, threadIdx.x);
}

// ---------------- Fused MoE weight transpose-cast --------------------------
// z<8: dp expert z  [2048][1024] -> dpT [1024][2048]  (bx<16, by<32)
// z>=8: gup expert z-8 [1024][4096] -> gupT [4096][1024] (bx<64, by<16)
__global__ __launch_bounds__(256) void tcast_moe_kernel(
    const float* __restrict__ dp, const float* __restrict__ gup,
    __hip_bfloat16* __restrict__ dpT, __hip_bfloat16* __restrict__ gupT) {
  int z = blockIdx.z;
  if (z < 8) {
    if (blockIdx.x >= 16) return;
    tcast_body(dp + (size_t)z * 2048 * 1024, dpT + (size_t)z * 1024 * 2048,
               2048, 1024, blockIdx.x, blockIdx.y, threadIdx.x);
  } else {
    if (blockIdx.y >= 16) return;
    tcast_body(gup + (size_t)(z - 8) * 1024 * 4096,
               gupT + (size_t)(z - 8) * 4096 * 1024,
               1024, 4096, blockIdx.x, blockIdx.y, threadIdx.x);
  }
}

// ---------------- MFMA bf16 GEMM: C[M,N] = A[M,K] @ Bt[N,K]^T --------------
// BK=32 double-buffered with COUNTED vmcnt prefetch (T3+T4): STAGE(s+1)
// issued before compute(s); s_waitcnt vmcnt(4) keeps the 4 new loads in
// flight across the barrier. MFMA order per acc identical to prior rounds.
template <int MODE>
__global__ __launch_bounds__(256, 4) void mfma_gemm(
    const __hip_bfloat16* __restrict__ A,
    const __hip_bfloat16* __restrict__ Bt,
    float* __restrict__ Cf, __hip_bfloat16* __restrict__ Cb,
    const float* __restrict__ addend, const float* __restrict__ bias,
    const int* __restrict__ counts, const int* __restrict__ offsets,
    const int* __restrict__ tos, int M0, int N, int K) {
  int e = blockIdx.z;
  int M = M0, off = 0;
  if (MODE >= 2) { M = counts[e]; off = offsets[e]; }
  int row0 = blockIdx.y * 128;
  if (row0 >= M) return;
  int n0 = blockIdx.x * 128;
  const __hip_bfloat16* Bte = Bt + (size_t)e * ((size_t)N * K);
  __shared__ __align__(16) __hip_bfloat16 sA[2][128 * 32];
  __shared__ __align__(16) __hip_bfloat16 sB[2][128 * 32];
  int t = threadIdx.x;
  int lane = t & 63;
  int wm = t >> 7, wn = (t >> 6) & 1;
  f32x4 acc[4][4] = {};

  int arow[2];
#pragma unroll
  for (int i = 0; i < 2; ++i) {
    int rg = row0 + i * 64 + (t >> 2);
    int ar;
    if (MODE == 2)      ar = (rg < M) ? tos[off + rg] : tos[off];
    else if (MODE == 3) ar = off + ((rg < M) ? rg : 0);
    else                ar = rg;
    arow[i] = ar;
  }
  int brow0 = n0 + (t >> 2);
  int kc = (t & 3) * 8;
  int rt = t >> 2;
  const __hip_bfloat16* aBase0 = A + (size_t)arow[0] * K + kc;
  const __hip_bfloat16* aBase1 = A + (size_t)arow[1] * K + kc;
  const __hip_bfloat16* bBase0 = Bte + (size_t)brow0 * K + kc;
  const __hip_bfloat16* bBase1 = Bte + (size_t)(brow0 + 64) * K + kc;

#define STAGE_HALF(buf, s)                                                 \
  do {                                                                     \
    int kk_ = (s) * 32;                                                    \
    gload_lds16(aBase0 + kk_, sA[buf] + rt * 32 + kc);                     \
    gload_lds16(bBase0 + kk_, sB[buf] + rt * 32 + kc);                     \
    gload_lds16(aBase1 + kk_, sA[buf] + (64 + rt) * 32 + kc);              \
    gload_lds16(bBase1 + kk_, sB[buf] + (64 + rt) * 32 + kc);              \
  } while (0)

  int nsteps = K / 32;
  STAGE_HALF(0, 0);
  for (int s = 0; s < nsteps; ++s) {
    int cur = s & 1;
    if (s + 1 < nsteps) {
      STAGE_HALF(cur ^ 1, s + 1);
      asm volatile("s_waitcnt vmcnt(4)" ::: "memory");
    } else {
      asm volatile("s_waitcnt vmcnt(0)" ::: "memory");
    }
    asm volatile("s_barrier" ::: "memory");
    {
      const __hip_bfloat16* sa = sA[cur];
      const __hip_bfloat16* sb = sB[cur];
      bf16x8 af[4], bfr[4];
#pragma unroll
      for (int mi = 0; mi < 4; ++mi)
        af[mi] = *(const bf16x8*)(sa + (wm * 64 + mi * 16 + (lane & 15)) * 32 + (lane >> 4) * 8);
#pragma unroll
      for (int ni = 0; ni < 4; ++ni)
        bfr[ni] = *(const bf16x8*)(sb + (wn * 64 + ni * 16 + (lane & 15)) * 32 + (lane >> 4) * 8);
#pragma unroll
      for (int mi = 0; mi < 4; ++mi)
#pragma unroll
        for (int ni = 0; ni < 4; ++ni)
          acc[mi][ni] = __builtin_amdgcn_mfma_f32_16x16x32_bf16(af[mi], bfr[ni], acc[mi][ni], 0, 0, 0);
    }
    asm volatile("s_barrier" ::: "memory");
  }
#undef STAGE_HALF

#pragma unroll
  for (int mi = 0; mi < 4; ++mi) {
#pragma unroll
    for (int ni = 0; ni < 4; ++ni) {
      int col = n0 + wn * 64 + ni * 16 + (lane & 15);
#pragma unroll
      for (int j = 0; j < 4; ++j) {
        float v = acc[mi][ni][j];
        int rg = row0 + wm * 64 + mi * 16 + (lane >> 4) * 4 + j;
        if (MODE == 0) {
          Cf[(size_t)rg * N + col] = v;
        } else if (MODE == 1) {
          Cf[(size_t)rg * N + col] = v + addend[(size_t)rg * N + col];
        } else if (MODE == 2) {
          float other = __shfl_xor(v, 1);
          if (!(lane & 1) && rg < M) {
            float gate = fminf(v + bias[(size_t)e * N + col], LIMITV);
            float up = fminf(fmaxf(other + bias[(size_t)e * N + col + 1], -LIMITV), LIMITV);
            float glu = gate / (1.f + __expf(-gate * ALPHAV));
            Cb[(size_t)(off + rg) * (N / 2) + (col >> 1)] = __float2bfloat16((up + 1.f) * glu);
          }
        } else {
          if (rg < M)
            Cf[(size_t)(off + rg) * N + col] = v + bias[(size_t)e * N + col];
        }
      }
    }
  }
}

// ---------------- RoPE + hi/lo split cast ----------------------------------
__global__ __launch_bounds__(512) void rope_cast_kernel(
    const float* __restrict__ qkv, const float* __restrict__ sins,
    const float* __restrict__ coss,
    __hip_bfloat16* __restrict__ qhi, __hip_bfloat16* __restrict__ qlo,
    __hip_bfloat16* __restrict__ khi, __hip_bfloat16* __restrict__ klo) {
  int s = blockIdx.x, t = threadIdx.x;
  const float* rowp = qkv + (size_t)s * 1536;
  int hh = t >> 5, j = t & 31;
  float c = coss[s * 32 + j], sn = sins[s * 32 + j];
  {
    float xr = rowp[hh * 64 + j], xi = rowp[hh * 64 + 32 + j];
    float y0 = xr * c - xi * sn;
    float y1 = xr * sn + xi * c;
    size_t i0 = (size_t)s * 1024 + hh * 64 + j;
    __hip_bfloat16 h0 = __float2bfloat16(y0);
    __hip_bfloat16 h1 = __float2bfloat16(y1);
    qhi[i0] = h0;      qlo[i0] = __float2bfloat16(y0 - __bfloat162float(h0));
    qhi[i0 + 32] = h1; qlo[i0 + 32] = __float2bfloat16(y1 - __bfloat162float(h1));
  }
  if (t < 128) {
    int kh = t >> 5;
    float xr = rowp[1024 + kh * 64 + j], xi = rowp[1024 + kh * 64 + 32 + j];
    float y0 = xr * c - xi * sn;
    float y1 = xr * sn + xi * c;
    size_t i0 = (size_t)kh * 131072 + s * 64 + j;
    __hip_bfloat16 h0 = __float2bfloat16(y0);
    __hip_bfloat16 h1 = __float2bfloat16(y1);
    khi[i0] = h0;      klo[i0] = __float2bfloat16(y0 - __bfloat162float(h0));
    khi[i0 + 32] = h1; klo[i0 + 32] = __float2bfloat16(y1 - __bfloat162float(h1));
  }
}

// ---------------- V transpose + counts zero --------------------------------
__global__ void vtrans_kernel(const float* __restrict__ qkv,
                              __hip_bfloat16* __restrict__ vT,
                              int* __restrict__ counts) {
  if (blockIdx.x == 0 && blockIdx.y == 0 && blockIdx.z == 0 && threadIdx.x < 8)
    counts[threadIdx.x] = 0;
  __shared__ float tile[32][33];
  int kh = blockIdx.z;
  int d0 = blockIdx.x * 32;
  int s0 = blockIdx.y * 32;
  int tx = threadIdx.x & 31, ty = threadIdx.x >> 5;  // ty 0..7
#pragma unroll
  for (int j = 0; j < 4; ++j)
    tile[ty * 4 + j][tx] =
        qkv[(size_t)(s0 + ty * 4 + j) * 1536 + 1280 + kh * 64 + d0 + tx];
  __syncthreads();
#pragma unroll
  for (int j = 0; j < 4; ++j)
    vT[(size_t)kh * 131072 + (size_t)(d0 + ty * 4 + j) * 2048 + s0 + tx] =
        __float2bfloat16(tile[tx][ty * 4 + j]);
}

// ---------------- attn softmax helper (swapped layout, in-register) --------
__device__ __forceinline__ void swsm(
    f32x4* sacc, float (*p)[4], int kv0, bool last, int qr, int g,
    float& m, float& l, float* af4, f32x4* acc_o) {
  float smax = -1e30f;
#pragma unroll
  for (int n = 0; n < 4; ++n)
#pragma unroll
    for (int j = 0; j < 4; ++j) {
      float s = sacc[n][j] * 0.125f;
      if (last && (kv0 + n * 16 + g * 4 + j) > qr) s = -1e30f;
      p[n][j] = s;
      smax = fmaxf(smax, s);
    }
  smax = fmaxf(smax, __shfl_xor(smax, 16));
  smax = fmaxf(smax, __shfl_xor(smax, 32));
  float mnew = fmaxf(m, smax);
  float a = __expf(m - mnew);
  float rs = 0.f;
#pragma unroll
  for (int n = 0; n < 4; ++n)
#pragma unroll
    for (int j = 0; j < 4; ++j) {
      float e2 = __expf(p[n][j] - mnew);
      p[n][j] = e2;
      rs += e2;
    }
  rs += __shfl_xor(rs, 16);
  rs += __shfl_xor(rs, 32);
  l = l * a + rs;
  m = mnew;
#pragma unroll
  for (int j = 0; j < 4; ++j) af4[j] = __shfl(a, g * 4 + j);
#pragma unroll
  for (int n2 = 0; n2 < 4; ++n2)
#pragma unroll
    for (int j = 0; j < 4; ++j) acc_o[n2][j] *= af4[j];
}

__device__ __forceinline__ void build_pfrag(
    float (*p)[4], int s2, int H0, int H1, int nsel, bf16x8& Ah, bf16x8& Al) {
  unsigned int pkh[2][2], pkl[2][2];
#pragma unroll
  for (int nn = 0; nn < 2; ++nn) {
#pragma unroll
    for (int d = 0; d < 2; ++d) {
      float p0 = p[2 * s2 + nn][2 * d], p1 = p[2 * s2 + nn][2 * d + 1];
      unsigned short h0 = bf16_bits(p0), h1 = bf16_bits(p1);
      pkh[nn][d] = (unsigned int)h0 | ((unsigned int)h1 << 16);
      float l0 = p0 - bf16u_to_f(h0), l1 = p1 - bf16u_to_f(h1);
      pkl[nn][d] = (unsigned int)bf16_bits(l0) | ((unsigned int)bf16_bits(l1) << 16);
    }
  }
  union { unsigned int u[4]; bf16x8 v; } AhU, AlU;
#pragma unroll
  for (int d = 0; d < 2; ++d) {
    unsigned int x0 = (unsigned int)__shfl((int)pkh[0][d], H0);
    unsigned int x1 = (unsigned int)__shfl((int)pkh[1][d], H0);
    AhU.u[d] = nsel ? x1 : x0;
    unsigned int y0 = (unsigned int)__shfl((int)pkh[0][d], H1);
    unsigned int y1 = (unsigned int)__shfl((int)pkh[1][d], H1);
    AhU.u[2 + d] = nsel ? y1 : y0;
    unsigned int z0 = (unsigned int)__shfl((int)pkl[0][d], H0);
    unsigned int z1 = (unsigned int)__shfl((int)pkl[1][d], H0);
    AlU.u[d] = nsel ? z1 : z0;
    unsigned int w0 = (unsigned int)__shfl((int)pkl[0][d], H1);
    unsigned int w1 = (unsigned int)__shfl((int)pkl[1][d], H1);
    AlU.u[2 + d] = nsel ? w1 : w0;
  }
  Ah = AhU.v;
  Al = AlU.v;
}

// ---------------- MFMA flash attention: head-pair batched, phase-batched ---
__global__ __launch_bounds__(128) void mfma_attn(
    const __hip_bfloat16* __restrict__ qhi, const __hip_bfloat16* __restrict__ qlo,
    const __hip_bfloat16* __restrict__ khi, const __hip_bfloat16* __restrict__ klo,
    const __hip_bfloat16* __restrict__ vT,  // [4][64][S]
    float* __restrict__ pacc,               // [8][S][1024] unnormalized O
    float* __restrict__ pm,                 // [8][16][S]
    float* __restrict__ pl) {               // [8][16][S]
  int hp = blockIdx.y;
  int h0 = 2 * hp, h1 = 2 * hp + 1, kh = hp >> 1;
  int ck = blockIdx.z;
  int wq = threadIdx.x >> 6;
  int qb = 2 * blockIdx.x + wq;
  if (16 * ck > qb) return;   // per-wave; no barriers in this kernel
  int lane = threadIdx.x & 63;
  int g = lane >> 4, q = lane & 15;
  int qrow0 = qb * 16;
  const int koff = g * 8;

  bf16x8 bqhA[2], bqlA[2], bqhB[2], bqlB[2];
  {
    size_t qoA = (size_t)(qrow0 + q) * 1024 + h0 * 64;
    bqhA[0] = *(const bf16x8*)(qhi + qoA + koff);
    bqhA[1] = *(const bf16x8*)(qhi + qoA + 32 + koff);
    bqlA[0] = *(const bf16x8*)(qlo + qoA + koff);
    bqlA[1] = *(const bf16x8*)(qlo + qoA + 32 + koff);
    size_t qoB = qoA + 64;
    bqhB[0] = *(const bf16x8*)(qhi + qoB + koff);
    bqhB[1] = *(const bf16x8*)(qhi + qoB + 32 + koff);
    bqlB[0] = *(const bf16x8*)(qlo + qoB + koff);
    bqlB[1] = *(const bf16x8*)(qlo + qoB + 32 + koff);
  }
  f32x4 accA[4] = {}, accB[4] = {};
  float mA = -1e30f, lA = 0.f, mB = -1e30f, lB = 0.f;
  const size_t kbase = (size_t)kh * (SS * 64) + (size_t)q * 64 + koff;
  const __hip_bfloat16* khp = khi + kbase;
  const __hip_bfloat16* klp = klo + kbase;
  const __hip_bfloat16* vfp =
      vT + (size_t)kh * (64 * SS) + (size_t)q * SS + koff;

  int ntiles = qb / 4 + 1;
  int lastT = ntiles - 1;
  int t0 = 4 * ck;
  int t1 = 4 * ck + 4; if (t1 > ntiles) t1 = ntiles;

  const int H0s = ((2 * g) & 3) * 16 + q;
  const int H1s = ((2 * g + 1) & 3) * 16 + q;
  const int nsel = (g >> 1) & 1;
  int qr = qrow0 + q;

  for (int tile = t0; tile < t1; ++tile) {
    int kv0 = tile * 64;
    bool last = (tile == lastT);

    bf16x8 kfh[4][2], kfl[4][2];
#pragma unroll
    for (int n = 0; n < 4; ++n)
#pragma unroll
      for (int step = 0; step < 2; ++step) {
        size_t ko = (size_t)(kv0 + n * 16) * 64 + step * 32;
        kfh[n][step] = *(const bf16x8*)(khp + ko);
        kfl[n][step] = *(const bf16x8*)(klp + ko);
      }

    f32x4 sA[4] = {}, sB[4] = {};
    __builtin_amdgcn_s_setprio(1);
#pragma unroll
    for (int n = 0; n < 4; ++n) {
#pragma unroll
      for (int step = 0; step < 2; ++step) {
        sA[n] = __builtin_amdgcn_mfma_f32_16x16x32_bf16(kfh[n][step], bqhA[step], sA[n], 0, 0, 0);
        sB[n] = __builtin_amdgcn_mfma_f32_16x16x32_bf16(kfh[n][step], bqhB[step], sB[n], 0, 0, 0);
        sA[n] = __builtin_amdgcn_mfma_f32_16x16x32_bf16(kfl[n][step], bqhA[step], sA[n], 0, 0, 0);
        sB[n] = __builtin_amdgcn_mfma_f32_16x16x32_bf16(kfl[n][step], bqhB[step], sB[n], 0, 0, 0);
        sA[n] = __builtin_amdgcn_mfma_f32_16x16x32_bf16(kfh[n][step], bqlA[step], sA[n], 0, 0, 0);
        sB[n] = __builtin_amdgcn_mfma_f32_16x16x32_bf16(kfh[n][step], bqlB[step], sB[n], 0, 0, 0);
      }
    }
    __builtin_amdgcn_s_setprio(0);

    bf16x8 vf[4][2];
#pragma unroll
    for (int s2 = 0; s2 < 2; ++s2)
#pragma unroll
      for (int n2 = 0; n2 < 4; ++n2)
        vf[n2][s2] = *(const bf16x8*)(vfp + (size_t)(n2 * 16) * SS + kv0 + s2 * 32);

    float pA[4][4], pB[4][4];
    float af4[4];
    swsm(sA, pA, kv0, last, qr, g, mA, lA, af4, accA);
    swsm(sB, pB, kv0, last, qr, g, mB, lB, af4, accB);

#pragma unroll
    for (int s2 = 0; s2 < 2; ++s2) {
      bf16x8 AhA, AlA, AhB, AlB;
      build_pfrag(pA, s2, H0s, H1s, nsel, AhA, AlA);
      build_pfrag(pB, s2, H0s, H1s, nsel, AhB, AlB);
      __builtin_amdgcn_s_setprio(1);
#pragma unroll
      for (int n2 = 0; n2 < 4; ++n2) {
        accA[n2] = __builtin_amdgcn_mfma_f32_16x16x32_bf16(AhA, vf[n2][s2], accA[n2], 0, 0, 0);
        accB[n2] = __builtin_amdgcn_mfma_f32_16x16x32_bf16(AhB, vf[n2][s2], accB[n2], 0, 0, 0);
        accA[n2] = __builtin_amdgcn_mfma_f32_16x16x32_bf16(AlA, vf[n2][s2], accA[n2], 0, 0, 0);
        accB[n2] = __builtin_amdgcn_mfma_f32_16x16x32_bf16(AlB, vf[n2][s2], accB[n2], 0, 0, 0);
      }
      __builtin_amdgcn_s_setprio(0);
    }
  }

#pragma unroll
  for (int n2 = 0; n2 < 4; ++n2) {
#pragma unroll
    for (int j = 0; j < 4; ++j) {
      int row = qrow0 + g * 4 + j;
      size_t base = ((size_t)ck * SS + row) * 1024 + n2 * 16 + q;
      pacc[base + h0 * 64] = accA[n2][j];
      pacc[base + h1 * 64] = accB[n2][j];
    }
  }
  if (lane < 16) {
    pm[(ck * 16 + h0) * SS + qrow0 + lane] = mA;
    pl[(ck * 16 + h0) * SS + qrow0 + lane] = lA;
  } else if (lane < 32) {
    pm[(ck * 16 + h1) * SS + qrow0 + (lane - 16)] = mB;
    pl[(ck * 16 + h1) * SS + qrow0 + (lane - 16)] = lB;
  }
}

// ---------------- Attention merge: combine <=8 kv-chunk partials -----------
__global__ __launch_bounds__(256) void attn_merge(
    const float* __restrict__ pacc, const float* __restrict__ pm,
    const float* __restrict__ pl, __hip_bfloat16* __restrict__ o) {
  int r = blockIdx.x;
  int t = threadIdx.x;
  int col = t * 4;
  int h = col >> 6;
  int nch = r / 256 + 1;
  float M = -1e30f;
  for (int c = 0; c < nch; ++c) M = fmaxf(M, pm[(c * 16 + h) * SS + r]);
  float L = 0.f;
  float4 acc = {0.f, 0.f, 0.f, 0.f};
  for (int c = 0; c < nch; ++c) {
    float w = __expf(pm[(c * 16 + h) * SS + r] - M);
    L += w * pl[(c * 16 + h) * SS + r];
    float4 a = *(const float4*)(pacc + ((size_t)c * SS + r) * 1024 + col);
    acc.x += w * a.x; acc.y += w * a.y; acc.z += w * a.z; acc.w += w * a.w;
  }
  float inv = 1.f / L;
  __hip_bfloat16* d = o + (size_t)r * 1024 + col;
  d[0] = __float2bfloat16(acc.x * inv);
  d[1] = __float2bfloat16(acc.y * inv);
  d[2] = __float2bfloat16(acc.z * inv);
  d[3] = __float2bfloat16(acc.w * inv);
}

// ---------------- Router: 4 waves/block, 1 token/wave, vectorized ----------
__global__ __launch_bounds__(256) void router_kernel(
    const float* __restrict__ xn2, const float* __restrict__ wr,
    const float* __restrict__ br,
    int* __restrict__ tok_e, float* __restrict__ tok_w,
    int* __restrict__ counts) {
  int wv = threadIdx.x >> 6, lane = threadIdx.x & 63;
  int tok = blockIdx.x * 4 + wv;
  const float* x = xn2 + (size_t)tok * HH;
  float acc[NEXP] = {};
#pragma unroll
  for (int p = 0; p < 4; ++p) {
    int d0 = p * 256 + lane * 4;
    float4 xv = *(const float4*)(x + d0);
    float xs[4] = {xv.x, xv.y, xv.z, xv.w};
#pragma unroll
    for (int dd = 0; dd < 4; ++dd) {
      const float4* wrow = (const float4*)(wr + (size_t)(d0 + dd) * NEXP);
      float4 w0 = wrow[0], w1 = wrow[1];
      acc[0] += xs[dd] * w0.x; acc[1] += xs[dd] * w0.y;
      acc[2] += xs[dd] * w0.z; acc[3] += xs[dd] * w0.w;
      acc[4] += xs[dd] * w1.x; acc[5] += xs[dd] * w1.y;
      acc[6] += xs[dd] * w1.z; acc[7] += xs[dd] * w1.w;
    }
  }
  float lg[NEXP];
#pragma unroll
  for (int e = 0; e < NEXP; ++e) lg[e] = wave_reduce_sum(acc[e]) + br[e];
  if (lane == 0) {
    int e0 = 0; float v0 = lg[0];
#pragma unroll
    for (int e = 1; e < NEXP; ++e) if (lg[e] > v0) { v0 = lg[e]; e0 = e; }
    int e1 = -1; float v1 = -1e30f;
#pragma unroll
    for (int e = 0; e < NEXP; ++e)
      if (e != e0 && lg[e] > v1) { v1 = lg[e]; e1 = e; }
    float z = __expf(v1 - v0);
    float w0 = 1.f / (1.f + z);
    tok_e[2 * tok] = e0; tok_e[2 * tok + 1] = e1;
    tok_w[2 * tok] = w0; tok_w[2 * tok + 1] = 1.f - w0;
    atomicAdd(&counts[e0], 1);
    atomicAdd(&counts[e1], 1);
  }
}

__global__ void offsets_kernel(const int* __restrict__ counts,
                               int* __restrict__ offsets, int* __restrict__ cursor) {
  int s = 0;
#pragma unroll
  for (int e = 0; e < NEXP; ++e) { offsets[e] = s; s += counts[e]; cursor[e] = 0; }
}

__global__ void scatter_kernel(const int* __restrict__ tok_e,
                               const int* __restrict__ offsets, int* __restrict__ cursor,
                               int* __restrict__ token_of_slot,
                               int* __restrict__ slot_of_token) {
  int tok = blockIdx.x * 64 + threadIdx.x;
#pragma unroll
  for (int s2 = 0; s2 < 2; ++s2) {
    int e = tok_e[2 * tok + s2];
    int pos = atomicAdd(&cursor[e], 1);
    int g = offsets[e] + pos;
    token_of_slot[g] = tok;
    slot_of_token[2 * tok + s2] = g;
  }
}

// ---------------- Final combine -------------------------------------------
__global__ void combine_kernel(const float* __restrict__ resid2,
                               const float* __restrict__ dout,
                               const int* __restrict__ slot_of_token,
                               const float* __restrict__ tok_w,
                               float* __restrict__ out) {
  int tok = blockIdx.x;
  int g0 = slot_of_token[2 * tok], g1 = slot_of_token[2 * tok + 1];
  float w0 = tok_w[2 * tok], w1 = tok_w[2 * tok + 1];
  int i = threadIdx.x;
  float4 r = ((const float4*)(resid2 + (size_t)tok * HH))[i];
  float4 a = ((const float4*)(dout + (size_t)g0 * HH))[i];
  float4 b = ((const float4*)(dout + (size_t)g1 * HH))[i];
  float4 o;
  o.x = r.x + w0 * a.x + w1 * b.x;
  o.y = r.y + w0 * a.y + w1 * b.y;
  o.z = r.z + w0 * a.z + w1 * b.z;
  o.w = r.w + w0 * a.w + w1 * b.w;
  ((float4*)(out + (size_t)tok * HH))[i] = o;
}

extern "C" void kernel_launch(void* const* d_in, const int* in_sizes, int n_in,
                              void* d_out, int out_size, void* d_ws, size_t ws_size,
                              hipStream_t stream) {
  const float* hidden = (const float*)d_in[0];
  const float* sins   = (const float*)d_in[1];
  const float* coss   = (const float*)d_in[2];
  const float* ln1_w  = (const float*)d_in[4];
  const float* ln2_w  = (const float*)d_in[5];
  const float* wq     = (const float*)d_in[6];
  const float* wk     = (const float*)d_in[7];
  const float* wv     = (const float*)d_in[8];
  const float* wo     = (const float*)d_in[9];
  const float* w_router = (const float*)d_in[10];
  const float* b_router = (const float*)d_in[11];
  const float* gup    = (const float*)d_in[12];
  const float* gub    = (const float*)d_in[13];
  const float* dp     = (const float*)d_in[14];
  const float* db     = (const float*)d_in[15];
  float* out = (float*)d_out;

  float* ws = (float*)d_ws;
  float* resid2 = ws;                                      // 2,097,152 f
  float* xn2    = resid2 + 2097152;                        // 2,097,152 f
  __hip_bfloat16* xn2b = (__hip_bfloat16*)(xn2 + 2097152); // 2M bf16
  float* pa = xn2 + 2097152 + 1048576;
  __hip_bfloat16* xn1b = (__hip_bfloat16*)pa;              // [0, 1,048,576) f
  __hip_bfloat16* qlo_b = (__hip_bfloat16*)pa;             // over xn1b (dead by rope)
  float* qkv = pa + 1048576;                               // [1,048,576, 4,194,304)
  __hip_bfloat16* qkvT = (__hip_bfloat16*)(pa + 4194304);  // [4,194,304, 4,980,736)
  __hip_bfloat16* woT  = qkvT + 1572864;                   // [4,980,736, 5,505,024)
  __hip_bfloat16* qhi_b = (__hip_bfloat16*)(pa + 5505024); // [5,505,024, 6,553,600)
  __hip_bfloat16* khi_b = qhi_b + 2097152;                 // [6,553,600, 6,815,744)
  __hip_bfloat16* vTb  = khi_b + 524288;                   // [6,815,744, 7,077,888)
  __hip_bfloat16* attnb = (__hip_bfloat16*)(pa + 7077888); // [7,077,888, 8,126,464)
  __hip_bfloat16* klo_b = (__hip_bfloat16*)(pa + 8126464); // [8,126,464, 8,388,608)
  __hip_bfloat16* dpT = (__hip_bfloat16*)pa;               // phase B: [0, 8,388,608)
  float* pb = pa + 8388608;
  __hip_bfloat16* gupT = (__hip_bfloat16*)pb;              // 33.55M bf16 (phase B)
  float* pacc = pb;                                        // 8*2048*1024 f (phase A)
  float* pm_b = pb + 16777216;                             // 262,144 f
  float* pl_b = pm_b + 262144;                             // 262,144 f
  __hip_bfloat16* gatedb = gupT + 33554432;                // 8.39M bf16
  float* dout = pb + 16777216 + 4194304;                   // 4,194,304 f
  float* tok_w = dout + 4194304;
  int* counts = (int*)(tok_w + 4096);
  int* offsets = counts + 8;
  int* cursor = offsets + 8;
  int* tok_e = cursor + 8;
  int* token_of_slot = tok_e + 4096;
  int* slot_of_token = token_of_slot + 4096;

  rmsnorm_kernel<<<SS, 256, 0, stream>>>(hidden, ln1_w, nullptr, xn1b);
  tcast4_kernel<<<dim3(16, 16, 4), 256, 0, stream>>>(wq, wk, wv, wo, qkvT, woT);
  mfma_gemm<0><<<dim3(12, 16, 1), 256, 0, stream>>>(
      xn1b, qkvT, qkv, nullptr, nullptr, nullptr, nullptr, nullptr, nullptr, SS, 1536, 1024);
  rope_cast_kernel<<<SS, 512, 0, stream>>>(qkv, sins, coss, qhi_b, qlo_b, khi_b, klo_b);
  vtrans_kernel<<<dim3(2, 64, 4), 256, 0, stream>>>(qkv, vTb, counts);
  mfma_attn<<<dim3(64, 8, 8), 128, 0, stream>>>(
      qhi_b, qlo_b, khi_b, klo_b, vTb, pacc, pm_b, pl_b);
  attn_merge<<<SS, 256, 0, stream>>>(pacc, pm_b, pl_b, attnb);
  mfma_gemm<1><<<dim3(8, 16, 1), 256, 0, stream>>>(
      attnb, woT, resid2, nullptr, hidden, nullptr, nullptr, nullptr, nullptr, SS, 1024, 1024);
  rmsnorm_kernel<<<SS, 256, 0, stream>>>(resid2, ln2_w, xn2, xn2b);
  tcast_moe_kernel<<<dim3(64, 32, 16), 256, 0, stream>>>(dp, gup, dpT, gupT);
  router_kernel<<<SS / 4, 256, 0, stream>>>(xn2, w_router, b_router, tok_e, tok_w, counts);
  offsets_kernel<<<1, 1, 0, stream>>>(counts, offsets, cursor);
  scatter_kernel<<<SS / 64, 64, 0, stream>>>(tok_e, offsets, cursor, token_of_slot, slot_of_token);
  mfma_gemm<2><<<dim3(32, 16, NEXP), 256, 0, stream>>>(
      xn2b, gupT, nullptr, gatedb, nullptr, gub, counts, offsets, token_of_slot, 0, 4096, 1024);
  mfma_gemm<3><<<dim3(8, 16, NEXP), 256, 0, stream>>>(
      gatedb, dpT, dout, nullptr, nullptr, db, counts, offsets, nullptr, 0, 1024, 2048);
  combine_kernel<<<SS, 256, 0, stream>>>(resid2, dout, slot_of_token, tok_w, out);
}

// Round 19
// 437.046 us; speedup vs baseline: 1.0576x; 1.0576x over previous
//
#include <hip/hip_runtime.h>
#include <hip/hip_bf16.h>
#include <math.h>

#define SS 2048
#define HH 1024
#define NHEADS 16
#define NKVH 4
#define HDIM 64
#define NEXP 8
#define FDIM 2048

static constexpr float EPSV   = 1e-6f;
static constexpr float ALPHAV = 1.702f;
static constexpr float LIMITV = 7.0f;

typedef __attribute__((ext_vector_type(8))) short bf16x8;
typedef __attribute__((ext_vector_type(4))) float f32x4;

__device__ __forceinline__ float wave_reduce_sum(float v) {
#pragma unroll
  for (int off = 32; off; off >>= 1) v += __shfl_xor(v, off);
  return v;
}

__device__ __forceinline__ unsigned short bf16_bits(float x) {
  __hip_bfloat16 h = __float2bfloat16(x);
  return *reinterpret_cast<unsigned short*>(&h);
}

__device__ __forceinline__ float bf16u_to_f(unsigned short u) {
  union { unsigned int i; float f; } c;
  c.i = ((unsigned int)u) << 16;
  return c.f;
}

__device__ __forceinline__ void gload_lds16(const __hip_bfloat16* g, __hip_bfloat16* s) {
  __builtin_amdgcn_global_load_lds(
      (const __attribute__((address_space(1))) void*)g,
      (__attribute__((address_space(3))) void*)s, 16, 0, 0);
}

// ---------------- RMSNorm: fp32 in, optional fp32 out + bf16 out -----------
__global__ void rmsnorm_kernel(const float* __restrict__ x,
                               const float* __restrict__ w,
                               float* __restrict__ o32,
                               __hip_bfloat16* __restrict__ o16) {
  int row = blockIdx.x;
  int t = threadIdx.x;
  const float4 v = ((const float4*)(x + (size_t)row * HH))[t];
  float ss = v.x * v.x + v.y * v.y + v.z * v.z + v.w * v.w;
  ss = wave_reduce_sum(ss);
  __shared__ float parts[4];
  if ((t & 63) == 0) parts[t >> 6] = ss;
  __syncthreads();
  float tot = parts[0] + parts[1] + parts[2] + parts[3];
  float r = rsqrtf(tot * (1.0f / HH) + EPSV);
  const float4 ww = ((const float4*)w)[t];
  float4 out;
  out.x = v.x * r * ww.x;
  out.y = v.y * r * ww.y;
  out.z = v.z * r * ww.z;
  out.w = v.w * r * ww.w;
  if (o32) ((float4*)(o32 + (size_t)row * HH))[t] = out;
  __hip_bfloat16* d = o16 + (size_t)row * HH + t * 4;
  d[0] = __float2bfloat16(out.x);
  d[1] = __float2bfloat16(out.y);
  d[2] = __float2bfloat16(out.z);
  d[3] = __float2bfloat16(out.w);
}

// ---------------- Transpose-cast 64x64 core --------------------------------
__device__ __forceinline__ void tcast_body(
    const float* __restrict__ ip, __hip_bfloat16* __restrict__ op,
    int R, int C, int bx, int by, int tid) {
  __shared__ float tile[64][65];
  int c0 = bx * 64, r0 = by * 64;
  int tx = tid & 15, ty = tid >> 4;
#pragma unroll
  for (int j = 0; j < 4; ++j) {
    int row = ty + j * 16;
    float4 v = *(const float4*)(ip + (size_t)(r0 + row) * C + c0 + tx * 4);
    tile[row][tx * 4 + 0] = v.x;
    tile[row][tx * 4 + 1] = v.y;
    tile[row][tx * 4 + 2] = v.z;
    tile[row][tx * 4 + 3] = v.w;
  }
  __syncthreads();
#pragma unroll
  for (int j = 0; j < 4; ++j) {
    int crow = ty + j * 16;
    ushort4 o;
    o.x = bf16_bits(tile[tx * 4 + 0][crow]);
    o.y = bf16_bits(tile[tx * 4 + 1][crow]);
    o.z = bf16_bits(tile[tx * 4 + 2][crow]);
    o.w = bf16_bits(tile[tx * 4 + 3][crow]);
    *(ushort4*)(op + (size_t)(c0 + crow) * R + r0 + tx * 4) = o;
  }
}

// ---------------- Fused 4-weight transpose-cast (attention weights) --------
__global__ __launch_bounds__(256) void tcast4_kernel(
    const float* __restrict__ wq, const float* __restrict__ wk,
    const float* __restrict__ wv, const float* __restrict__ wo,
    __hip_bfloat16* __restrict__ qkvT, __hip_bfloat16* __restrict__ woT) {
  int z = blockIdx.z;
  const float* in;
  __hip_bfloat16* out;
  int C;
  if (z == 0)      { in = wq; out = qkvT;                C = 1024; }
  else if (z == 1) { in = wk; out = qkvT + 1024 * 1024;  C = 256; }
  else if (z == 2) { in = wv; out = qkvT + 1280 * 1024;  C = 256; }
  else             { in = wo; out = woT;                 C = 1024; }
  if (blockIdx.x * 64 >= C) return;
  tcast_body(in, out, 1024, C, blockIdx.x, blockIdx.y, threadIdx.x);
}

// ---------------- Fused MoE weight transpose-cast (flattened 1D grid) ------
// bid < 4096: dp tile (e=bid/512; tile 16x32 grid); else gup tile (e, 64x16).
__global__ __launch_bounds__(256) void tcast_moe_kernel(
    const float* __restrict__ dp, const float* __restrict__ gup,
    __hip_bfloat16* __restrict__ dpT, __hip_bfloat16* __restrict__ gupT) {
  int bid = blockIdx.x;
  if (bid < 4096) {
    int e = bid >> 9, rem = bid & 511;
    int bx = rem & 15, by = rem >> 4;  // bx<16, by<32
    tcast_body(dp + (size_t)e * 2048 * 1024, dpT + (size_t)e * 1024 * 2048,
               2048, 1024, bx, by, threadIdx.x);
  } else {
    int r2 = bid - 4096;
    int e = r2 >> 10, rem = r2 & 1023;
    int bx = rem & 63, by = rem >> 6;  // bx<64, by<16
    tcast_body(gup + (size_t)e * 1024 * 4096, gupT + (size_t)e * 4096 * 1024,
               1024, 4096, bx, by, threadIdx.x);
  }
}

// ---------------- MFMA bf16 GEMM: C[M,N] = A[M,K] @ Bt[N,K]^T --------------
// BK=64 as two interleaved BK=32 stages (4x [128][32] LDS buffers) — the
// proven r17 structure (8 loads in flight per thread per barrier interval).
template <int MODE>
__global__ __launch_bounds__(256, 4) void mfma_gemm(
    const __hip_bfloat16* __restrict__ A,
    const __hip_bfloat16* __restrict__ Bt,
    float* __restrict__ Cf, __hip_bfloat16* __restrict__ Cb,
    const float* __restrict__ addend, const float* __restrict__ bias,
    const int* __restrict__ counts, const int* __restrict__ offsets,
    const int* __restrict__ tos, int M0, int N, int K) {
  int e = blockIdx.z;
  int M = M0, off = 0;
  if (MODE >= 2) { M = counts[e]; off = offsets[e]; }
  int row0 = blockIdx.y * 128;
  if (row0 >= M) return;
  int n0 = blockIdx.x * 128;
  const __hip_bfloat16* Bte = Bt + (size_t)e * ((size_t)N * K);
  __shared__ __align__(16) __hip_bfloat16 sA0[128 * 32];
  __shared__ __align__(16) __hip_bfloat16 sA1[128 * 32];
  __shared__ __align__(16) __hip_bfloat16 sB0[128 * 32];
  __shared__ __align__(16) __hip_bfloat16 sB1[128 * 32];
  int t = threadIdx.x;
  int lane = t & 63;
  int wm = t >> 7, wn = (t >> 6) & 1;
  f32x4 acc[4][4] = {};

  int arow[2];
#pragma unroll
  for (int i = 0; i < 2; ++i) {
    int rg = row0 + i * 64 + (t >> 2);
    int ar;
    if (MODE == 2)      ar = (rg < M) ? tos[off + rg] : tos[off];
    else if (MODE == 3) ar = off + ((rg < M) ? rg : 0);
    else                ar = rg;
    arow[i] = ar;
  }
  int brow0 = n0 + (t >> 2);
  int kc = (t & 3) * 8;

  for (int k0 = 0; k0 < K; k0 += 64) {
#pragma unroll
    for (int i = 0; i < 2; ++i) {
      int r = i * 64 + (t >> 2);
      const __hip_bfloat16* ap = A + (size_t)arow[i] * K + k0 + kc;
      const __hip_bfloat16* bp = Bte + (size_t)(brow0 + i * 64) * K + k0 + kc;
      gload_lds16(ap, sA0 + r * 32 + kc);
      gload_lds16(ap + 32, sA1 + r * 32 + kc);
      gload_lds16(bp, sB0 + r * 32 + kc);
      gload_lds16(bp + 32, sB1 + r * 32 + kc);
    }
    __syncthreads();
#pragma unroll
    for (int half = 0; half < 2; ++half) {
      const __hip_bfloat16* sa = half ? sA1 : sA0;
      const __hip_bfloat16* sb = half ? sB1 : sB0;
      bf16x8 af[4], bfr[4];
#pragma unroll
      for (int mi = 0; mi < 4; ++mi)
        af[mi] = *(const bf16x8*)(sa + (wm * 64 + mi * 16 + (lane & 15)) * 32 + (lane >> 4) * 8);
#pragma unroll
      for (int ni = 0; ni < 4; ++ni)
        bfr[ni] = *(const bf16x8*)(sb + (wn * 64 + ni * 16 + (lane & 15)) * 32 + (lane >> 4) * 8);
#pragma unroll
      for (int mi = 0; mi < 4; ++mi)
#pragma unroll
        for (int ni = 0; ni < 4; ++ni)
          acc[mi][ni] = __builtin_amdgcn_mfma_f32_16x16x32_bf16(af[mi], bfr[ni], acc[mi][ni], 0, 0, 0);
    }
    __syncthreads();
  }

#pragma unroll
  for (int mi = 0; mi < 4; ++mi) {
#pragma unroll
    for (int ni = 0; ni < 4; ++ni) {
      int col = n0 + wn * 64 + ni * 16 + (lane & 15);
#pragma unroll
      for (int j = 0; j < 4; ++j) {
        float v = acc[mi][ni][j];
        int rg = row0 + wm * 64 + mi * 16 + (lane >> 4) * 4 + j;
        if (MODE == 0) {
          Cf[(size_t)rg * N + col] = v;
        } else if (MODE == 1) {
          Cf[(size_t)rg * N + col] = v + addend[(size_t)rg * N + col];
        } else if (MODE == 2) {
          float other = __shfl_xor(v, 1);
          if (!(lane & 1) && rg < M) {
            float gate = fminf(v + bias[(size_t)e * N + col], LIMITV);
            float up = fminf(fmaxf(other + bias[(size_t)e * N + col + 1], -LIMITV), LIMITV);
            float glu = gate / (1.f + __expf(-gate * ALPHAV));
            Cb[(size_t)(off + rg) * (N / 2) + (col >> 1)] = __float2bfloat16((up + 1.f) * glu);
          }
        } else {
          if (rg < M)
            Cf[(size_t)(off + rg) * N + col] = v + bias[(size_t)e * N + col];
        }
      }
    }
  }
}

// ---------------- RoPE + hi/lo split cast ----------------------------------
__global__ __launch_bounds__(512) void rope_cast_kernel(
    const float* __restrict__ qkv, const float* __restrict__ sins,
    const float* __restrict__ coss,
    __hip_bfloat16* __restrict__ qhi, __hip_bfloat16* __restrict__ qlo,
    __hip_bfloat16* __restrict__ khi, __hip_bfloat16* __restrict__ klo) {
  int s = blockIdx.x, t = threadIdx.x;
  const float* rowp = qkv + (size_t)s * 1536;
  int hh = t >> 5, j = t & 31;
  float c = coss[s * 32 + j], sn = sins[s * 32 + j];
  {
    float xr = rowp[hh * 64 + j], xi = rowp[hh * 64 + 32 + j];
    float y0 = xr * c - xi * sn;
    float y1 = xr * sn + xi * c;
    size_t i0 = (size_t)s * 1024 + hh * 64 + j;
    __hip_bfloat16 h0 = __float2bfloat16(y0);
    __hip_bfloat16 h1 = __float2bfloat16(y1);
    qhi[i0] = h0;      qlo[i0] = __float2bfloat16(y0 - __bfloat162float(h0));
    qhi[i0 + 32] = h1; qlo[i0 + 32] = __float2bfloat16(y1 - __bfloat162float(h1));
  }
  if (t < 128) {
    int kh = t >> 5;
    float xr = rowp[1024 + kh * 64 + j], xi = rowp[1024 + kh * 64 + 32 + j];
    float y0 = xr * c - xi * sn;
    float y1 = xr * sn + xi * c;
    size_t i0 = (size_t)kh * 131072 + s * 64 + j;
    __hip_bfloat16 h0 = __float2bfloat16(y0);
    __hip_bfloat16 h1 = __float2bfloat16(y1);
    khi[i0] = h0;      klo[i0] = __float2bfloat16(y0 - __bfloat162float(h0));
    khi[i0 + 32] = h1; klo[i0 + 32] = __float2bfloat16(y1 - __bfloat162float(h1));
  }
}

// ---------------- V transpose + counts zero --------------------------------
__global__ void vtrans_kernel(const float* __restrict__ qkv,
                              __hip_bfloat16* __restrict__ vT,
                              int* __restrict__ counts) {
  if (blockIdx.x == 0 && blockIdx.y == 0 && blockIdx.z == 0 && threadIdx.x < 8)
    counts[threadIdx.x] = 0;
  __shared__ float tile[32][33];
  int kh = blockIdx.z;
  int d0 = blockIdx.x * 32;
  int s0 = blockIdx.y * 32;
  int tx = threadIdx.x & 31, ty = threadIdx.x >> 5;  // ty 0..7
#pragma unroll
  for (int j = 0; j < 4; ++j)
    tile[ty * 4 + j][tx] =
        qkv[(size_t)(s0 + ty * 4 + j) * 1536 + 1280 + kh * 64 + d0 + tx];
  __syncthreads();
#pragma unroll
  for (int j = 0; j < 4; ++j)
    vT[(size_t)kh * 131072 + (size_t)(d0 + ty * 4 + j) * 2048 + s0 + tx] =
        __float2bfloat16(tile[tx][ty * 4 + j]);
}

// ---------------- attn softmax helper (swapped layout, in-register) --------
__device__ __forceinline__ void swsm(
    f32x4* sacc, float (*p)[4], int kv0, bool last, int qr, int g,
    float& m, float& l, float* af4, f32x4* acc_o) {
  float smax = -1e30f;
#pragma unroll
  for (int n = 0; n < 4; ++n)
#pragma unroll
    for (int j = 0; j < 4; ++j) {
      float s = sacc[n][j] * 0.125f;
      if (last && (kv0 + n * 16 + g * 4 + j) > qr) s = -1e30f;
      p[n][j] = s;
      smax = fmaxf(smax, s);
    }
  smax = fmaxf(smax, __shfl_xor(smax, 16));
  smax = fmaxf(smax, __shfl_xor(smax, 32));
  float mnew = fmaxf(m, smax);
  float a = __expf(m - mnew);
  float rs = 0.f;
#pragma unroll
  for (int n = 0; n < 4; ++n)
#pragma unroll
    for (int j = 0; j < 4; ++j) {
      float e2 = __expf(p[n][j] - mnew);
      p[n][j] = e2;
      rs += e2;
    }
  rs += __shfl_xor(rs, 16);
  rs += __shfl_xor(rs, 32);
  l = l * a + rs;
  m = mnew;
#pragma unroll
  for (int j = 0; j < 4; ++j) af4[j] = __shfl(a, g * 4 + j);
#pragma unroll
  for (int n2 = 0; n2 < 4; ++n2)
#pragma unroll
    for (int j = 0; j < 4; ++j) acc_o[n2][j] *= af4[j];
}

__device__ __forceinline__ void build_pfrag(
    float (*p)[4], int s2, int H0, int H1, int nsel, bf16x8& Ah, bf16x8& Al) {
  unsigned int pkh[2][2], pkl[2][2];
#pragma unroll
  for (int nn = 0; nn < 2; ++nn) {
#pragma unroll
    for (int d = 0; d < 2; ++d) {
      float p0 = p[2 * s2 + nn][2 * d], p1 = p[2 * s2 + nn][2 * d + 1];
      unsigned short h0 = bf16_bits(p0), h1 = bf16_bits(p1);
      pkh[nn][d] = (unsigned int)h0 | ((unsigned int)h1 << 16);
      float l0 = p0 - bf16u_to_f(h0), l1 = p1 - bf16u_to_f(h1);
      pkl[nn][d] = (unsigned int)bf16_bits(l0) | ((unsigned int)bf16_bits(l1) << 16);
    }
  }
  union { unsigned int u[4]; bf16x8 v; } AhU, AlU;
#pragma unroll
  for (int d = 0; d < 2; ++d) {
    unsigned int x0 = (unsigned int)__shfl((int)pkh[0][d], H0);
    unsigned int x1 = (unsigned int)__shfl((int)pkh[1][d], H0);
    AhU.u[d] = nsel ? x1 : x0;
    unsigned int y0 = (unsigned int)__shfl((int)pkh[0][d], H1);
    unsigned int y1 = (unsigned int)__shfl((int)pkh[1][d], H1);
    AhU.u[2 + d] = nsel ? y1 : y0;
    unsigned int z0 = (unsigned int)__shfl((int)pkl[0][d], H0);
    unsigned int z1 = (unsigned int)__shfl((int)pkl[1][d], H0);
    AlU.u[d] = nsel ? z1 : z0;
    unsigned int w0 = (unsigned int)__shfl((int)pkl[0][d], H1);
    unsigned int w1 = (unsigned int)__shfl((int)pkl[1][d], H1);
    AlU.u[2 + d] = nsel ? w1 : w0;
  }
  Ah = AhU.v;
  Al = AlU.v;
}

// ---------------- MFMA flash attention: head-pair batched, phase-batched ---
__global__ __launch_bounds__(128) void mfma_attn(
    const __hip_bfloat16* __restrict__ qhi, const __hip_bfloat16* __restrict__ qlo,
    const __hip_bfloat16* __restrict__ khi, const __hip_bfloat16* __restrict__ klo,
    const __hip_bfloat16* __restrict__ vT,  // [4][64][S]
    float* __restrict__ pacc,               // [8][S][1024] unnormalized O
    float* __restrict__ pm,                 // [8][16][S]
    float* __restrict__ pl) {               // [8][16][S]
  int hp = blockIdx.y;
  int h0 = 2 * hp, h1 = 2 * hp + 1, kh = hp >> 1;
  int ck = blockIdx.z;
  int wq = threadIdx.x >> 6;
  int qb = 2 * blockIdx.x + wq;
  if (16 * ck > qb) return;   // per-wave; no barriers in this kernel
  int lane = threadIdx.x & 63;
  int g = lane >> 4, q = lane & 15;
  int qrow0 = qb * 16;
  const int koff = g * 8;

  bf16x8 bqhA[2], bqlA[2], bqhB[2], bqlB[2];
  {
    size_t qoA = (size_t)(qrow0 + q) * 1024 + h0 * 64;
    bqhA[0] = *(const bf16x8*)(qhi + qoA + koff);
    bqhA[1] = *(const bf16x8*)(qhi + qoA + 32 + koff);
    bqlA[0] = *(const bf16x8*)(qlo + qoA + koff);
    bqlA[1] = *(const bf16x8*)(qlo + qoA + 32 + koff);
    size_t qoB = qoA + 64;
    bqhB[0] = *(const bf16x8*)(qhi + qoB + koff);
    bqhB[1] = *(const bf16x8*)(qhi + qoB + 32 + koff);
    bqlB[0] = *(const bf16x8*)(qlo + qoB + koff);
    bqlB[1] = *(const bf16x8*)(qlo + qoB + 32 + koff);
  }
  f32x4 accA[4] = {}, accB[4] = {};
  float mA = -1e30f, lA = 0.f, mB = -1e30f, lB = 0.f;
  const size_t kbase = (size_t)kh * (SS * 64) + (size_t)q * 64 + koff;
  const __hip_bfloat16* khp = khi + kbase;
  const __hip_bfloat16* klp = klo + kbase;
  const __hip_bfloat16* vfp =
      vT + (size_t)kh * (64 * SS) + (size_t)q * SS + koff;

  int ntiles = qb / 4 + 1;
  int lastT = ntiles - 1;
  int t0 = 4 * ck;
  int t1 = 4 * ck + 4; if (t1 > ntiles) t1 = ntiles;

  const int H0s = ((2 * g) & 3) * 16 + q;
  const int H1s = ((2 * g + 1) & 3) * 16 + q;
  const int nsel = (g >> 1) & 1;
  int qr = qrow0 + q;

  for (int tile = t0; tile < t1; ++tile) {
    int kv0 = tile * 64;
    bool last = (tile == lastT);

    bf16x8 kfh[4][2], kfl[4][2];
#pragma unroll
    for (int n = 0; n < 4; ++n)
#pragma unroll
      for (int step = 0; step < 2; ++step) {
        size_t ko = (size_t)(kv0 + n * 16) * 64 + step * 32;
        kfh[n][step] = *(const bf16x8*)(khp + ko);
        kfl[n][step] = *(const bf16x8*)(klp + ko);
      }

    f32x4 sA[4] = {}, sB[4] = {};
    __builtin_amdgcn_s_setprio(1);
#pragma unroll
    for (int n = 0; n < 4; ++n) {
#pragma unroll
      for (int step = 0; step < 2; ++step) {
        sA[n] = __builtin_amdgcn_mfma_f32_16x16x32_bf16(kfh[n][step], bqhA[step], sA[n], 0, 0, 0);
        sB[n] = __builtin_amdgcn_mfma_f32_16x16x32_bf16(kfh[n][step], bqhB[step], sB[n], 0, 0, 0);
        sA[n] = __builtin_amdgcn_mfma_f32_16x16x32_bf16(kfl[n][step], bqhA[step], sA[n], 0, 0, 0);
        sB[n] = __builtin_amdgcn_mfma_f32_16x16x32_bf16(kfl[n][step], bqhB[step], sB[n], 0, 0, 0);
        sA[n] = __builtin_amdgcn_mfma_f32_16x16x32_bf16(kfh[n][step], bqlA[step], sA[n], 0, 0, 0);
        sB[n] = __builtin_amdgcn_mfma_f32_16x16x32_bf16(kfh[n][step], bqlB[step], sB[n], 0, 0, 0);
      }
    }
    __builtin_amdgcn_s_setprio(0);

    bf16x8 vf[4][2];
#pragma unroll
    for (int s2 = 0; s2 < 2; ++s2)
#pragma unroll
      for (int n2 = 0; n2 < 4; ++n2)
        vf[n2][s2] = *(const bf16x8*)(vfp + (size_t)(n2 * 16) * SS + kv0 + s2 * 32);

    float pA[4][4], pB[4][4];
    float af4[4];
    swsm(sA, pA, kv0, last, qr, g, mA, lA, af4, accA);
    swsm(sB, pB, kv0, last, qr, g, mB, lB, af4, accB);

#pragma unroll
    for (int s2 = 0; s2 < 2; ++s2) {
      bf16x8 AhA, AlA, AhB, AlB;
      build_pfrag(pA, s2, H0s, H1s, nsel, AhA, AlA);
      build_pfrag(pB, s2, H0s, H1s, nsel, AhB, AlB);
      __builtin_amdgcn_s_setprio(1);
#pragma unroll
      for (int n2 = 0; n2 < 4; ++n2) {
        accA[n2] = __builtin_amdgcn_mfma_f32_16x16x32_bf16(AhA, vf[n2][s2], accA[n2], 0, 0, 0);
        accB[n2] = __builtin_amdgcn_mfma_f32_16x16x32_bf16(AhB, vf[n2][s2], accB[n2], 0, 0, 0);
        accA[n2] = __builtin_amdgcn_mfma_f32_16x16x32_bf16(AlA, vf[n2][s2], accA[n2], 0, 0, 0);
        accB[n2] = __builtin_amdgcn_mfma_f32_16x16x32_bf16(AlB, vf[n2][s2], accB[n2], 0, 0, 0);
      }
      __builtin_amdgcn_s_setprio(0);
    }
  }

#pragma unroll
  for (int n2 = 0; n2 < 4; ++n2) {
#pragma unroll
    for (int j = 0; j < 4; ++j) {
      int row = qrow0 + g * 4 + j;
      size_t base = ((size_t)ck * SS + row) * 1024 + n2 * 16 + q;
      pacc[base + h0 * 64] = accA[n2][j];
      pacc[base + h1 * 64] = accB[n2][j];
    }
  }
  if (lane < 16) {
    pm[(ck * 16 + h0) * SS + qrow0 + lane] = mA;
    pl[(ck * 16 + h0) * SS + qrow0 + lane] = lA;
  } else if (lane < 32) {
    pm[(ck * 16 + h1) * SS + qrow0 + (lane - 16)] = mB;
    pl[(ck * 16 + h1) * SS + qrow0 + (lane - 16)] = lB;
  }
}

// ---------------- Attention merge: combine <=8 kv-chunk partials -----------
__global__ __launch_bounds__(256) void attn_merge(
    const float* __restrict__ pacc, const float* __restrict__ pm,
    const float* __restrict__ pl, __hip_bfloat16* __restrict__ o) {
  int r = blockIdx.x;
  int t = threadIdx.x;
  int col = t * 4;
  int h = col >> 6;
  int nch = r / 256 + 1;
  float M = -1e30f;
  for (int c = 0; c < nch; ++c) M = fmaxf(M, pm[(c * 16 + h) * SS + r]);
  float L = 0.f;
  float4 acc = {0.f, 0.f, 0.f, 0.f};
  for (int c = 0; c < nch; ++c) {
    float w = __expf(pm[(c * 16 + h) * SS + r] - M);
    L += w * pl[(c * 16 + h) * SS + r];
    float4 a = *(const float4*)(pacc + ((size_t)c * SS + r) * 1024 + col);
    acc.x += w * a.x; acc.y += w * a.y; acc.z += w * a.z; acc.w += w * a.w;
  }
  float inv = 1.f / L;
  __hip_bfloat16* d = o + (size_t)r * 1024 + col;
  d[0] = __float2bfloat16(acc.x * inv);
  d[1] = __float2bfloat16(acc.y * inv);
  d[2] = __float2bfloat16(acc.z * inv);
  d[3] = __float2bfloat16(acc.w * inv);
}

// ---------------- Router: 4 waves/block, 1 token/wave, vectorized ----------
__global__ __launch_bounds__(256) void router_kernel(
    const float* __restrict__ xn2, const float* __restrict__ wr,
    const float* __restrict__ br,
    int* __restrict__ tok_e, float* __restrict__ tok_w,
    int* __restrict__ counts) {
  int wv = threadIdx.x >> 6, lane = threadIdx.x & 63;
  int tok = blockIdx.x * 4 + wv;
  const float* x = xn2 + (size_t)tok * HH;
  float acc[NEXP] = {};
#pragma unroll
  for (int p = 0; p < 4; ++p) {
    int d0 = p * 256 + lane * 4;
    float4 xv = *(const float4*)(x + d0);
    float xs[4] = {xv.x, xv.y, xv.z, xv.w};
#pragma unroll
    for (int dd = 0; dd < 4; ++dd) {
      const float4* wrow = (const float4*)(wr + (size_t)(d0 + dd) * NEXP);
      float4 w0 = wrow[0], w1 = wrow[1];
      acc[0] += xs[dd] * w0.x; acc[1] += xs[dd] * w0.y;
      acc[2] += xs[dd] * w0.z; acc[3] += xs[dd] * w0.w;
      acc[4] += xs[dd] * w1.x; acc[5] += xs[dd] * w1.y;
      acc[6] += xs[dd] * w1.z; acc[7] += xs[dd] * w1.w;
    }
  }
  float lg[NEXP];
#pragma unroll
  for (int e = 0; e < NEXP; ++e) lg[e] = wave_reduce_sum(acc[e]) + br[e];
  if (lane == 0) {
    int e0 = 0; float v0 = lg[0];
#pragma unroll
    for (int e = 1; e < NEXP; ++e) if (lg[e] > v0) { v0 = lg[e]; e0 = e; }
    int e1 = -1; float v1 = -1e30f;
#pragma unroll
    for (int e = 0; e < NEXP; ++e)
      if (e != e0 && lg[e] > v1) { v1 = lg[e]; e1 = e; }
    float z = __expf(v1 - v0);
    float w0 = 1.f / (1.f + z);
    tok_e[2 * tok] = e0; tok_e[2 * tok + 1] = e1;
    tok_w[2 * tok] = w0; tok_w[2 * tok + 1] = 1.f - w0;
    atomicAdd(&counts[e0], 1);
    atomicAdd(&counts[e1], 1);
  }
}

__global__ void offsets_kernel(const int* __restrict__ counts,
                               int* __restrict__ offsets, int* __restrict__ cursor) {
  int s = 0;
#pragma unroll
  for (int e = 0; e < NEXP; ++e) { offsets[e] = s; s += counts[e]; cursor[e] = 0; }
}

__global__ void scatter_kernel(const int* __restrict__ tok_e,
                               const int* __restrict__ offsets, int* __restrict__ cursor,
                               int* __restrict__ token_of_slot,
                               int* __restrict__ slot_of_token) {
  int tok = blockIdx.x * 64 + threadIdx.x;
#pragma unroll
  for (int s2 = 0; s2 < 2; ++s2) {
    int e = tok_e[2 * tok + s2];
    int pos = atomicAdd(&cursor[e], 1);
    int g = offsets[e] + pos;
    token_of_slot[g] = tok;
    slot_of_token[2 * tok + s2] = g;
  }
}

// ---------------- Final combine -------------------------------------------
__global__ void combine_kernel(const float* __restrict__ resid2,
                               const float* __restrict__ dout,
                               const int* __restrict__ slot_of_token,
                               const float* __restrict__ tok_w,
                               float* __restrict__ out) {
  int tok = blockIdx.x;
  int g0 = slot_of_token[2 * tok], g1 = slot_of_token[2 * tok + 1];
  float w0 = tok_w[2 * tok], w1 = tok_w[2 * tok + 1];
  int i = threadIdx.x;
  float4 r = ((const float4*)(resid2 + (size_t)tok * HH))[i];
  float4 a = ((const float4*)(dout + (size_t)g0 * HH))[i];
  float4 b = ((const float4*)(dout + (size_t)g1 * HH))[i];
  float4 o;
  o.x = r.x + w0 * a.x + w1 * b.x;
  o.y = r.y + w0 * a.y + w1 * b.y;
  o.z = r.z + w0 * a.z + w1 * b.z;
  o.w = r.w + w0 * a.w + w1 * b.w;
  ((float4*)(out + (size_t)tok * HH))[i] = o;
}

extern "C" void kernel_launch(void* const* d_in, const int* in_sizes, int n_in,
                              void* d_out, int out_size, void* d_ws, size_t ws_size,
                              hipStream_t stream) {
  const float* hidden = (const float*)d_in[0];
  const float* sins   = (const float*)d_in[1];
  const float* coss   = (const float*)d_in[2];
  const float* ln1_w  = (const float*)d_in[4];
  const float* ln2_w  = (const float*)d_in[5];
  const float* wq     = (const float*)d_in[6];
  const float* wk     = (const float*)d_in[7];
  const float* wv     = (const float*)d_in[8];
  const float* wo     = (const float*)d_in[9];
  const float* w_router = (const float*)d_in[10];
  const float* b_router = (const float*)d_in[11];
  const float* gup    = (const float*)d_in[12];
  const float* gub    = (const float*)d_in[13];
  const float* dp     = (const float*)d_in[14];
  const float* db     = (const float*)d_in[15];
  float* out = (float*)d_out;

  float* ws = (float*)d_ws;
  float* resid2 = ws;                                      // 2,097,152 f
  float* xn2    = resid2 + 2097152;                        // 2,097,152 f
  __hip_bfloat16* xn2b = (__hip_bfloat16*)(xn2 + 2097152); // 2M bf16
  float* pa = xn2 + 2097152 + 1048576;
  __hip_bfloat16* xn1b = (__hip_bfloat16*)pa;              // [0, 1,048,576) f
  __hip_bfloat16* qlo_b = (__hip_bfloat16*)pa;             // over xn1b (dead by rope)
  float* qkv = pa + 1048576;                               // [1,048,576, 4,194,304)
  __hip_bfloat16* qkvT = (__hip_bfloat16*)(pa + 4194304);  // [4,194,304, 4,980,736)
  __hip_bfloat16* woT  = qkvT + 1572864;                   // [4,980,736, 5,505,024)
  __hip_bfloat16* qhi_b = (__hip_bfloat16*)(pa + 5505024); // [5,505,024, 6,553,600)
  __hip_bfloat16* khi_b = qhi_b + 2097152;                 // [6,553,600, 6,815,744)
  __hip_bfloat16* vTb  = khi_b + 524288;                   // [6,815,744, 7,077,888)
  __hip_bfloat16* attnb = (__hip_bfloat16*)(pa + 7077888); // [7,077,888, 8,126,464)
  __hip_bfloat16* klo_b = (__hip_bfloat16*)(pa + 8126464); // [8,126,464, 8,388,608)
  __hip_bfloat16* dpT = (__hip_bfloat16*)pa;               // phase B: [0, 8,388,608)
  float* pb = pa + 8388608;
  __hip_bfloat16* gupT = (__hip_bfloat16*)pb;              // 33.55M bf16 (phase B)
  float* pacc = pb;                                        // 8*2048*1024 f (phase A)
  float* pm_b = pb + 16777216;                             // 262,144 f
  float* pl_b = pm_b + 262144;                             // 262,144 f
  __hip_bfloat16* gatedb = gupT + 33554432;                // 8.39M bf16
  float* dout = pb + 16777216 + 4194304;                   // 4,194,304 f
  float* tok_w = dout + 4194304;
  int* counts = (int*)(tok_w + 4096);
  int* offsets = counts + 8;
  int* cursor = offsets + 8;
  int* tok_e = cursor + 8;
  int* token_of_slot = tok_e + 4096;
  int* slot_of_token = token_of_slot + 4096;

  rmsnorm_kernel<<<SS, 256, 0, stream>>>(hidden, ln1_w, nullptr, xn1b);
  tcast4_kernel<<<dim3(16, 16, 4), 256, 0, stream>>>(wq, wk, wv, wo, qkvT, woT);
  mfma_gemm<0><<<dim3(12, 16, 1), 256, 0, stream>>>(
      xn1b, qkvT, qkv, nullptr, nullptr, nullptr, nullptr, nullptr, nullptr, SS, 1536, 1024);
  rope_cast_kernel<<<SS, 512, 0, stream>>>(qkv, sins, coss, qhi_b, qlo_b, khi_b, klo_b);
  vtrans_kernel<<<dim3(2, 64, 4), 256, 0, stream>>>(qkv, vTb, counts);
  mfma_attn<<<dim3(64, 8, 8), 128, 0, stream>>>(
      qhi_b, qlo_b, khi_b, klo_b, vTb, pacc, pm_b, pl_b);
  attn_merge<<<SS, 256, 0, stream>>>(pacc, pm_b, pl_b, attnb);
  mfma_gemm<1><<<dim3(8, 16, 1), 256, 0, stream>>>(
      attnb, woT, resid2, nullptr, hidden, nullptr, nullptr, nullptr, nullptr, SS, 1024, 1024);
  rmsnorm_kernel<<<SS, 256, 0, stream>>>(resid2, ln2_w, xn2, xn2b);
  tcast_moe_kernel<<<12288, 256, 0, stream>>>(dp, gup, dpT, gupT);
  router_kernel<<<SS / 4, 256, 0, stream>>>(xn2, w_router, b_router, tok_e, tok_w, counts);
  offsets_kernel<<<1, 1, 0, stream>>>(counts, offsets, cursor);
  scatter_kernel<<<SS / 64, 64, 0, stream>>>(tok_e, offsets, cursor, token_of_slot, slot_of_token);
  mfma_gemm<2><<<dim3(32, 16, NEXP), 256, 0, stream>>>(
      xn2b, gupT, nullptr, gatedb, nullptr, gub, counts, offsets, token_of_slot, 0, 4096, 1024);
  mfma_gemm<3><<<dim3(8, 16, NEXP), 256, 0, stream>>>(
      gatedb, dpT, dout, nullptr, nullptr, db, counts, offsets, nullptr, 0, 1024, 2048);
  combine_kernel<<<SS, 256, 0, stream>>>(resid2, dout, slot_of_token, tok_w, out);
}